// Round 1
// baseline (304.906 us; speedup 1.0000x reference)
//
#include <hip/hip_runtime.h>
#include <hip/hip_bf16.h>

// Problem: B=8, C=512, T=4096, KC=VC=512, H=1, SCALE=512.
// Gram-trick pipeline:
//   sx[b,c]   = sum_t x[b,c,t]
//   G[b]      = x_b x_b^T                (bf16 MFMA, K=4096)
//   S2[b]     = Wv G[b]   ( = (G Wv^T)^T, NT since S2[v,c]=sum_c' Wv[v,c']G[c,c'] )
//   scores[b] = (Wqk S2^T + bqk tb^T + ta bv^T + T bqk bv^T)/512
//   p         = softmax_v(scores); pb[b,k]=sum_v p bv
//   M[b]      = p Wv                      (NT with WvT)
//   out[b]    = M[b] x_b + pb             (NT with xT)

#define BB 8
#define CC 512
#define TT 4096

typedef __attribute__((ext_vector_type(8))) short bf16x8;
typedef __attribute__((ext_vector_type(4))) float f32x4;

__device__ __forceinline__ void gload_lds16(const void* g, void* l) {
  __builtin_amdgcn_global_load_lds((const __attribute__((address_space(1))) void*)g,
                                   (__attribute__((address_space(3))) void*)l,
                                   16, 0, 0);
}

// ---------------- convert x -> bf16 [c,t] and bf16 transposed [t,c] ----------
__global__ __launch_bounds__(256)
void convert_x_kernel(const float* __restrict__ x, __hip_bfloat16* __restrict__ xh,
                      __hip_bfloat16* __restrict__ xhT)
{
  __shared__ float tile[32][33];
  const int b = blockIdx.z, c0 = blockIdx.y * 32, t0 = blockIdx.x * 32;
  const int tx = threadIdx.x & 31, ty = threadIdx.x >> 5;
#pragma unroll
  for (int j = 0; j < 4; j++) {
    int c = ty + j * 8;
    size_t gi = ((size_t)b * CC + (c0 + c)) * TT + t0 + tx;
    float v = x[gi];
    xh[gi] = __float2bfloat16(v);
    tile[c][tx] = v;
  }
  __syncthreads();
#pragma unroll
  for (int j = 0; j < 4; j++) {
    int t = ty + j * 8;
    xhT[((size_t)b * TT + (t0 + t)) * CC + c0 + tx] = __float2bfloat16(tile[tx][t]);
  }
}

// ---------------- row sums of x (fp32 exact) --------------------------------
__global__ __launch_bounds__(256)
void rowsum_kernel(const float* __restrict__ x, float* __restrict__ sx)
{
  const int row = blockIdx.x;  // b*CC + c
  float s = 0.f;
  for (int i = threadIdx.x; i < TT; i += 256) s += x[(size_t)row * TT + i];
#pragma unroll
  for (int off = 32; off; off >>= 1) s += __shfl_xor(s, off);
  __shared__ float red[4];
  if ((threadIdx.x & 63) == 0) red[threadIdx.x >> 6] = s;
  __syncthreads();
  if (threadIdx.x == 0) sx[row] = red[0] + red[1] + red[2] + red[3];
}

// ---------------- weights -> bf16 (and Wv transposed) -----------------------
__global__ __launch_bounds__(256)
void convert_w_kernel(const float* __restrict__ Wqk, const float* __restrict__ Wv,
                      __hip_bfloat16* __restrict__ Wqkh, __hip_bfloat16* __restrict__ Wvh,
                      __hip_bfloat16* __restrict__ WvT)
{
  int i = blockIdx.x * 256 + threadIdx.x;  // < 512*512
  Wqkh[i] = __float2bfloat16(Wqk[i]);
  float wv = Wv[i];
  Wvh[i] = __float2bfloat16(wv);
  WvT[(i & 511) * 512 + (i >> 9)] = __float2bfloat16(wv);
}

// ---------------- ta[b,k] = Wqk . sx_b ; tb[b,v] = Wv . sx_b ----------------
__global__ __launch_bounds__(256)
void tatb_kernel(const float* __restrict__ Wqk, const float* __restrict__ Wv,
                 const float* __restrict__ sx, float* __restrict__ ta, float* __restrict__ tb)
{
  int wid = threadIdx.x >> 6, lane = threadIdx.x & 63;
  int gid = blockIdx.x * 4 + wid;          // [0, 2*BB*512)
  int which = gid >> 12;                    // BB*512 = 4096
  int rem = gid & 4095;
  int b = rem >> 9, j = rem & 511;
  const float* W = which ? Wv : Wqk;
  float s = 0.f;
#pragma unroll
  for (int i = 0; i < 8; i++) {
    int c = lane + i * 64;
    s += W[j * 512 + c] * sx[b * 512 + c];
  }
#pragma unroll
  for (int off = 32; off; off >>= 1) s += __shfl_xor(s, off);
  if (lane == 0) (which ? tb : ta)[b * 512 + j] = s;
}

// ---------------- NT GEMM: C[M,N] = A[M,K] * B[N,K]^T, bf16 in, templated epilogue
// EPI 0: store bf16. EPI 1: scores epilogue (fp32). EPI 2: out epilogue (fp32 + pb).
template <int EPI>
__global__ __launch_bounds__(256)
void gemm_nt_kernel(const __hip_bfloat16* __restrict__ Aall, long strideA,
                    const __hip_bfloat16* __restrict__ Ball, long strideB,
                    void* __restrict__ Call, long strideC,
                    int M, int N, int K,
                    const float* __restrict__ p1, const float* __restrict__ p2,
                    const float* __restrict__ p3, const float* __restrict__ p4)
{
  const int b = blockIdx.z;
  const __hip_bfloat16* A = Aall + (size_t)b * strideA;
  const __hip_bfloat16* Bm = Ball + (size_t)b * strideB;
  const int tm = blockIdx.y, tn = blockIdx.x;

  __shared__ __align__(16) __hip_bfloat16 sA[128 * 64];
  __shared__ __align__(16) __hip_bfloat16 sB[128 * 64];

  const int tid = threadIdx.x;
  const int lane = tid & 63, wid = tid >> 6;
  const int wr = wid >> 1, wc = wid & 1;

  f32x4 acc[4][4];
#pragma unroll
  for (int m = 0; m < 4; m++)
#pragma unroll
    for (int n = 0; n < 4; n++) acc[m][n] = (f32x4){0.f, 0.f, 0.f, 0.f};

  for (int k0 = 0; k0 < K; k0 += 64) {
    // stage A,B tiles (128x64 bf16 each) via async global->LDS, 16B/lane/call
#pragma unroll
    for (int i = 0; i < 4; i++) {
      int e = tid * 8 + i * 2048;           // element index in tile
      int row = e >> 6, col = e & 63;
      int ebase = wid * 512 + i * 2048;     // wave-uniform LDS base element
      gload_lds16(A + (size_t)(tm * 128 + row) * K + k0 + col, &sA[ebase]);
      gload_lds16(Bm + (size_t)(tn * 128 + row) * K + k0 + col, &sB[ebase]);
    }
    __syncthreads();
#pragma unroll
    for (int ks = 0; ks < 2; ks++) {
      bf16x8 af[4], bfv[4];
      const int kb = ks * 32 + (lane >> 4) * 8;
#pragma unroll
      for (int m = 0; m < 4; m++)
        af[m] = *(const bf16x8*)&sA[(wr * 64 + m * 16 + (lane & 15)) * 64 + kb];
#pragma unroll
      for (int n = 0; n < 4; n++)
        bfv[n] = *(const bf16x8*)&sB[(wc * 64 + n * 16 + (lane & 15)) * 64 + kb];
#pragma unroll
      for (int m = 0; m < 4; m++)
#pragma unroll
        for (int n = 0; n < 4; n++)
          acc[m][n] = __builtin_amdgcn_mfma_f32_16x16x32_bf16(af[m], bfv[n], acc[m][n], 0, 0, 0);
    }
    __syncthreads();
  }

  // epilogue: C/D layout for 16x16x32: col = lane&15, row = (lane>>4)*4 + reg
  const int rb = tm * 128 + wr * 64 + ((lane >> 4) << 2);
  const int cb = tn * 128 + wc * 64 + (lane & 15);

  if (EPI == 0) {
    __hip_bfloat16* Cb = (__hip_bfloat16*)Call + (size_t)b * strideC;
#pragma unroll
    for (int m = 0; m < 4; m++)
#pragma unroll
      for (int n = 0; n < 4; n++)
#pragma unroll
        for (int r = 0; r < 4; r++) {
          int row = rb + m * 16 + r, col = cb + n * 16;
          Cb[(size_t)row * N + col] = __float2bfloat16(acc[m][n][r]);
        }
  } else if (EPI == 1) {
    float* Cf = (float*)Call + (size_t)b * strideC;
    const float* ta = p3 + b * 512;
    const float* tb = p4 + b * 512;
#pragma unroll
    for (int m = 0; m < 4; m++)
#pragma unroll
      for (int n = 0; n < 4; n++)
#pragma unroll
        for (int r = 0; r < 4; r++) {
          int row = rb + m * 16 + r, col = cb + n * 16;
          float bq = p1[row], bvv = p2[col];
          float v = acc[m][n][r] + bq * tb[col] + bvv * ta[row] + (float)TT * bq * bvv;
          Cf[(size_t)row * N + col] = v * (1.0f / 512.0f);
        }
  } else {
    float* Cf = (float*)Call + (size_t)b * strideC;
    const float* pb = p1 + b * 512;
#pragma unroll
    for (int m = 0; m < 4; m++)
#pragma unroll
      for (int n = 0; n < 4; n++)
#pragma unroll
        for (int r = 0; r < 4; r++) {
          int row = rb + m * 16 + r, col = cb + n * 16;
          Cf[(size_t)row * N + col] = acc[m][n][r] + pb[row];
        }
  }
}

// ---------------- softmax over v (512) + pb = p . bv ------------------------
__global__ __launch_bounds__(256)
void softmax_kernel(const float* __restrict__ scores, const float* __restrict__ bv,
                    __hip_bfloat16* __restrict__ p, float* __restrict__ pb)
{
  const int row = blockIdx.x;  // b*512 + k
  const int tid = threadIdx.x;
  const float s0 = scores[(size_t)row * 512 + tid];
  const float s1 = scores[(size_t)row * 512 + 256 + tid];
  __shared__ float red[4];

  float m = fmaxf(s0, s1);
#pragma unroll
  for (int off = 32; off; off >>= 1) m = fmaxf(m, __shfl_xor(m, off));
  if ((tid & 63) == 0) red[tid >> 6] = m;
  __syncthreads();
  m = fmaxf(fmaxf(red[0], red[1]), fmaxf(red[2], red[3]));

  float e0 = __expf(s0 - m), e1 = __expf(s1 - m);
  float s = e0 + e1;
#pragma unroll
  for (int off = 32; off; off >>= 1) s += __shfl_xor(s, off);
  __syncthreads();
  if ((tid & 63) == 0) red[tid >> 6] = s;
  __syncthreads();
  s = red[0] + red[1] + red[2] + red[3];
  float inv = 1.0f / s;

  float p0 = e0 * inv, p1v = e1 * inv;
  p[(size_t)row * 512 + tid] = __float2bfloat16(p0);
  p[(size_t)row * 512 + 256 + tid] = __float2bfloat16(p1v);

  float contrib = p0 * bv[tid] + p1v * bv[256 + tid];
#pragma unroll
  for (int off = 32; off; off >>= 1) contrib += __shfl_xor(contrib, off);
  __syncthreads();
  if ((tid & 63) == 0) red[tid >> 6] = contrib;
  __syncthreads();
  if (tid == 0) pb[row] = red[0] + red[1] + red[2] + red[3];
}

// ----------------------------------------------------------------------------
extern "C" void kernel_launch(void* const* d_in, const int* in_sizes, int n_in,
                              void* d_out, int out_size, void* d_ws, size_t ws_size,
                              hipStream_t stream)
{
  const float* x   = (const float*)d_in[0];
  const float* Wqk = (const float*)d_in[1];
  const float* bqk = (const float*)d_in[2];
  const float* Wv  = (const float*)d_in[3];
  const float* bv  = (const float*)d_in[4];
  float* out = (float*)d_out;

  char* w = (char*)d_ws;
  auto alloc = [&](size_t bytes) {
    void* pp = (void*)w;
    w += (bytes + 255) & ~(size_t)255;
    return pp;
  };
  __hip_bfloat16* xh     = (__hip_bfloat16*)alloc((size_t)BB * CC * TT * 2);
  __hip_bfloat16* xhT    = (__hip_bfloat16*)alloc((size_t)BB * TT * CC * 2);
  __hip_bfloat16* Gb     = (__hip_bfloat16*)alloc((size_t)BB * CC * CC * 2);
  __hip_bfloat16* S2     = (__hip_bfloat16*)alloc((size_t)BB * CC * CC * 2);
  float*          scores = (float*)alloc((size_t)BB * CC * CC * 4);
  __hip_bfloat16* pmat   = (__hip_bfloat16*)alloc((size_t)BB * CC * CC * 2);
  __hip_bfloat16* Mm     = (__hip_bfloat16*)alloc((size_t)BB * CC * CC * 2);
  __hip_bfloat16* Wqkh   = (__hip_bfloat16*)alloc((size_t)CC * CC * 2);
  __hip_bfloat16* Wvh    = (__hip_bfloat16*)alloc((size_t)CC * CC * 2);
  __hip_bfloat16* WvT    = (__hip_bfloat16*)alloc((size_t)CC * CC * 2);
  float* sx = (float*)alloc((size_t)BB * CC * 4);
  float* ta = (float*)alloc((size_t)BB * CC * 4);
  float* tb = (float*)alloc((size_t)BB * CC * 4);
  float* pb = (float*)alloc((size_t)BB * CC * 4);

  // 1) conversions + small precomputes
  convert_x_kernel<<<dim3(TT / 32, CC / 32, BB), 256, 0, stream>>>(x, xh, xhT);
  rowsum_kernel<<<BB * CC, 256, 0, stream>>>(x, sx);
  convert_w_kernel<<<(CC * CC) / 256, 256, 0, stream>>>(Wqk, Wv, Wqkh, Wvh, WvT);
  tatb_kernel<<<(2 * BB * CC) / 4 / 256 * 256 / 256, 256, 0, stream>>>(Wqk, Wv, sx, ta, tb);

  const long sXH = (long)CC * TT;   // 512*4096
  const long sSq = (long)CC * CC;   // 512*512

  // 2) G = x x^T  (M=N=512, K=4096)
  gemm_nt_kernel<0><<<dim3(4, 4, BB), 256, 0, stream>>>(
      xh, sXH, xh, sXH, Gb, sSq, 512, 512, 4096, nullptr, nullptr, nullptr, nullptr);

  // 3) S2 = Wv G  (S2[v,c] = sum_c' Wv[v,c'] G[c,c'] ; NT: A=Wvh, B=G)
  gemm_nt_kernel<0><<<dim3(4, 4, BB), 256, 0, stream>>>(
      Wvh, 0, Gb, sSq, S2, sSq, 512, 512, 512, nullptr, nullptr, nullptr, nullptr);

  // 4) scores = (Wqk S2^T + biases)/512  (NT: A=Wqkh, B=S2)
  gemm_nt_kernel<1><<<dim3(4, 4, BB), 256, 0, stream>>>(
      Wqkh, 0, S2, sSq, scores, sSq, 512, 512, 512, bqk, bv, ta, tb);

  // 5) softmax + pb
  softmax_kernel<<<BB * CC, 256, 0, stream>>>(scores, bv, pmat, pb);

  // 6) M = p Wv  (NT: A=p, B=WvT)
  gemm_nt_kernel<0><<<dim3(4, 4, BB), 256, 0, stream>>>(
      pmat, sSq, WvT, 0, Mm, sSq, 512, 512, 512, nullptr, nullptr, nullptr, nullptr);

  // 7) out = M x + pb  (NT: A=M, B=xhT; M=512, N=4096, K=512)
  gemm_nt_kernel<2><<<dim3(TT / 128, 4, BB), 256, 0, stream>>>(
      Mm, sSq, xhT, (long)TT * CC, out, (long)CC * TT, 512, 4096, 512,
      pb, nullptr, nullptr, nullptr);
}

// Round 2
// 237.463 us; speedup vs baseline: 1.2840x; 1.2840x over previous
//
#include <hip/hip_runtime.h>
#include <hip/hip_bf16.h>

// Gram-trick pipeline (B=8, C=512, T=4096, SCALE=512):
//   sx[b,c]   = sum_t x[b,c,t]                       (fused into convert_x)
//   G[b]      = x_b x_b^T                            (bf16 MFMA, split-K=4 + reduce)
//   S2[b]     = Wv G[b]                              (NT, 64^2 tiles)
//   scores[b] = (Wqk S2^T + bqk tb^T + ta bv^T + T bqk bv^T)/512
//   p         = softmax_v(scores); pb[b,k] = p . bv
//   M[b]      = p Wv                                 (NT with WvT)
//   out[b]    = M[b] x_b + pb                        (NT with xhT)

#define BB 8
#define CC 512
#define TT 4096

typedef __attribute__((ext_vector_type(8))) short bf16x8;
typedef __attribute__((ext_vector_type(4))) float f32x4;

__device__ __forceinline__ void gload_lds16(const void* g, void* l) {
  __builtin_amdgcn_global_load_lds((const __attribute__((address_space(1))) void*)g,
                                   (__attribute__((address_space(3))) void*)l,
                                   16, 0, 0);
}
__device__ __forceinline__ float bf2f(short u) {
  return __uint_as_float(((unsigned)(unsigned short)u) << 16);
}
__device__ __forceinline__ unsigned short f2bf(float f) {
  return __builtin_bit_cast(unsigned short, __float2bfloat16(f));
}

// ---- convert x -> bf16 [c,t] + bf16 [t,c], fused row-sum via atomics -------
__global__ __launch_bounds__(256)
void convert_x_kernel(const float* __restrict__ x, __hip_bfloat16* __restrict__ xh,
                      __hip_bfloat16* __restrict__ xhT, float* __restrict__ sx)
{
  __shared__ float tile[32][33];
  const int b = blockIdx.z, c0 = blockIdx.y * 32, t0 = blockIdx.x * 32;
  const int tid = threadIdx.x;
  {
    const int c = tid >> 3, t4 = (tid & 7) * 4;
    const size_t gi = ((size_t)b * CC + (c0 + c)) * TT + t0 + t4;
    const float4 v = *(const float4*)&x[gi];
    ushort4 h;
    h.x = f2bf(v.x); h.y = f2bf(v.y); h.z = f2bf(v.z); h.w = f2bf(v.w);
    *(ushort4*)&xh[gi] = h;
    tile[c][t4 + 0] = v.x; tile[c][t4 + 1] = v.y;
    tile[c][t4 + 2] = v.z; tile[c][t4 + 3] = v.w;
    float s = (v.x + v.y) + (v.z + v.w);
    s += __shfl_xor(s, 1); s += __shfl_xor(s, 2); s += __shfl_xor(s, 4);
    if ((tid & 7) == 0) atomicAdd(&sx[b * CC + c0 + c], s);
  }
  __syncthreads();
  {
    const int t = tid >> 3, c4 = (tid & 7) * 4;
    ushort4 h;
    h.x = f2bf(tile[c4 + 0][t]); h.y = f2bf(tile[c4 + 1][t]);
    h.z = f2bf(tile[c4 + 2][t]); h.w = f2bf(tile[c4 + 3][t]);
    *(ushort4*)&xhT[((size_t)b * TT + (t0 + t)) * CC + c0 + c4] = h;
  }
}

// ---- weights -> bf16 (and Wv transposed) -----------------------------------
__global__ __launch_bounds__(256)
void convert_w_kernel(const float* __restrict__ Wqk, const float* __restrict__ Wv,
                      __hip_bfloat16* __restrict__ Wqkh, __hip_bfloat16* __restrict__ Wvh,
                      __hip_bfloat16* __restrict__ WvT)
{
  int i = blockIdx.x * 256 + threadIdx.x;  // < 512*512
  Wqkh[i] = __float2bfloat16(Wqk[i]);
  float wv = Wv[i];
  Wvh[i] = __float2bfloat16(wv);
  WvT[(i & 511) * 512 + (i >> 9)] = __float2bfloat16(wv);
}

// ---- ta[b,k] = Wqk . sx_b ; tb[b,v] = Wv . sx_b ----------------------------
__global__ __launch_bounds__(256)
void tatb_kernel(const float* __restrict__ Wqk, const float* __restrict__ Wv,
                 const float* __restrict__ sx, float* __restrict__ ta, float* __restrict__ tb)
{
  int wid = threadIdx.x >> 6, lane = threadIdx.x & 63;
  int gid = blockIdx.x * 4 + wid;          // [0, 2*BB*512)
  int which = gid >> 12;                   // BB*512 = 4096
  int rem = gid & 4095;
  int b = rem >> 9, j = rem & 511;
  const float* W = which ? Wv : Wqk;
  float s = 0.f;
#pragma unroll
  for (int i = 0; i < 8; i++) {
    int c = lane + i * 64;
    s += W[j * 512 + c] * sx[b * 512 + c];
  }
#pragma unroll
  for (int off = 32; off; off >>= 1) s += __shfl_xor(s, off);
  if (lane == 0) (which ? tb : ta)[b * 512 + j] = s;
}

// ---- NT GEMM template: C[.,.] = A[M,K] B[N,K]^T ----------------------------
// LDS tiles XOR-swizzled (col ^ ((row&7)<<3) in elements); global source is
// pre-swizzled so global_load_lds' linear lane->dest order lands correctly.
// Block decode goes through an XCD-chunked swizzle (nwg % 8 == 0 required).
// Split-K: blockIdx.z = b*nslices + ks; C offset uses z*strideC.
// EPI 0: bf16 store. EPI 1: scores epilogue (f32). EPI 2: out epilogue (f32+pb).
template <int BM, int BN, int EPI>
__global__ __launch_bounds__(256)
void gemm_nt_kernel(const __hip_bfloat16* __restrict__ A, long strideA, int ldA,
                    const __hip_bfloat16* __restrict__ B, long strideB, int ldB,
                    void* __restrict__ C, long strideC, int ldC,
                    int Kslice, int nslices,
                    const float* __restrict__ p1, const float* __restrict__ p2,
                    const float* __restrict__ p3, const float* __restrict__ p4)
{
  constexpr int FM = BM / 32, FN = BN / 32;
  const int tid = threadIdx.x, lane = tid & 63, wid = tid >> 6;

  // XCD-chunked block swizzle
  const int gx = gridDim.x, gy = gridDim.y;
  const int lin = blockIdx.x + gx * (blockIdx.y + gy * blockIdx.z);
  const int nwg = gx * gy * (int)gridDim.z;
  const int lin2 = (lin & 7) * (nwg >> 3) + (lin >> 3);
  const int tn = lin2 % gx;
  const int r1 = lin2 / gx;
  const int tm = r1 % gy;
  const int z  = r1 / gy;
  const int b  = z / nslices;
  const int ks = z - b * nslices;

  const __hip_bfloat16* Ab = A + (size_t)b * strideA + (size_t)(tm * BM) * ldA + (size_t)ks * Kslice;
  const __hip_bfloat16* Bb = B + (size_t)b * strideB + (size_t)(tn * BN) * ldB + (size_t)ks * Kslice;

  __shared__ __align__(16) __hip_bfloat16 sA[BM * 64];
  __shared__ __align__(16) __hip_bfloat16 sB[BN * 64];

  const int wr = wid >> 1, wc = wid & 1;

  f32x4 acc[FM][FN];
#pragma unroll
  for (int m = 0; m < FM; m++)
#pragma unroll
    for (int n = 0; n < FN; n++) acc[m][n] = (f32x4){0.f, 0.f, 0.f, 0.f};

  for (int k0 = 0; k0 < Kslice; k0 += 64) {
#pragma unroll
    for (int i = 0; i < BM / 32; i++) {
      int e = tid * 8 + i * 2048;
      int row = e >> 6;
      int colg = (e & 63) ^ ((row & 7) << 3);   // inverse-swizzled global col
      gload_lds16(Ab + (size_t)row * ldA + k0 + colg, &sA[wid * 512 + i * 2048]);
    }
#pragma unroll
    for (int i = 0; i < BN / 32; i++) {
      int e = tid * 8 + i * 2048;
      int row = e >> 6;
      int colg = (e & 63) ^ ((row & 7) << 3);
      gload_lds16(Bb + (size_t)row * ldB + k0 + colg, &sB[wid * 512 + i * 2048]);
    }
    __syncthreads();
#pragma unroll
    for (int ks2 = 0; ks2 < 2; ks2++) {
      bf16x8 af[FM], bfv[FN];
      const int kb = ks2 * 32 + (lane >> 4) * 8;
#pragma unroll
      for (int m = 0; m < FM; m++) {
        int row = wr * (BM / 2) + m * 16 + (lane & 15);
        af[m] = *(const bf16x8*)&sA[row * 64 + (kb ^ ((row & 7) << 3))];
      }
#pragma unroll
      for (int n = 0; n < FN; n++) {
        int row = wc * (BN / 2) + n * 16 + (lane & 15);
        bfv[n] = *(const bf16x8*)&sB[row * 64 + (kb ^ ((row & 7) << 3))];
      }
#pragma unroll
      for (int m = 0; m < FM; m++)
#pragma unroll
        for (int n = 0; n < FN; n++)
          acc[m][n] = __builtin_amdgcn_mfma_f32_16x16x32_bf16(af[m], bfv[n], acc[m][n], 0, 0, 0);
    }
    __syncthreads();
  }

  // epilogue: C/D layout 16x16x32: col = lane&15, row = (lane>>4)*4 + reg
  const int rb = tm * BM + wr * (BM / 2) + ((lane >> 4) << 2);
  const int cb = tn * BN + wc * (BN / 2) + (lane & 15);

  if (EPI == 0) {
    __hip_bfloat16* Cb = (__hip_bfloat16*)C + (size_t)z * strideC;
#pragma unroll
    for (int m = 0; m < FM; m++)
#pragma unroll
      for (int n = 0; n < FN; n++)
#pragma unroll
        for (int r = 0; r < 4; r++) {
          int row = rb + m * 16 + r, col = cb + n * 16;
          Cb[(size_t)row * ldC + col] = __float2bfloat16(acc[m][n][r]);
        }
  } else if (EPI == 1) {
    float* Cf = (float*)C + (size_t)z * strideC;
    const float* ta = p3 + b * 512;
    const float* tb = p4 + b * 512;
#pragma unroll
    for (int m = 0; m < FM; m++)
#pragma unroll
      for (int n = 0; n < FN; n++)
#pragma unroll
        for (int r = 0; r < 4; r++) {
          int row = rb + m * 16 + r, col = cb + n * 16;
          float bq = p1[row], bvv = p2[col];
          float v = acc[m][n][r] + bq * tb[col] + bvv * ta[row] + (float)TT * bq * bvv;
          Cf[(size_t)row * ldC + col] = v * (1.0f / 512.0f);
        }
  } else {
    float* Cf = (float*)C + (size_t)z * strideC;
    const float* pb = p1 + b * 512;
#pragma unroll
    for (int m = 0; m < FM; m++)
#pragma unroll
      for (int n = 0; n < FN; n++)
#pragma unroll
        for (int r = 0; r < 4; r++) {
          int row = rb + m * 16 + r, col = cb + n * 16;
          Cf[(size_t)row * ldC + col] = acc[m][n][r] + pb[row];
        }
  }
}

// ---- reduce split-K bf16 partials -> bf16 G --------------------------------
__global__ __launch_bounds__(256)
void reduce_g_kernel(const short* __restrict__ Gpart, short* __restrict__ Gb)
{
  const int idx = (blockIdx.x * 256 + threadIdx.x) * 8;  // < BB*262144
  const int b = idx >> 18, i = idx & 262143;
  const short* base = Gpart + ((size_t)(b * 4) << 18) + i;
  float s[8];
#pragma unroll
  for (int q = 0; q < 8; q++) s[q] = 0.f;
#pragma unroll
  for (int ks = 0; ks < 4; ks++) {
    bf16x8 v = *(const bf16x8*)(base + ((size_t)ks << 18));
#pragma unroll
    for (int q = 0; q < 8; q++) s[q] += bf2f(v[q]);
  }
  bf16x8 o;
#pragma unroll
  for (int q = 0; q < 8; q++) o[q] = (short)f2bf(s[q]);
  *(bf16x8*)(Gb + ((size_t)b << 18) + i) = o;
}

// ---- softmax over v (512) + pb = p . bv ------------------------------------
__global__ __launch_bounds__(256)
void softmax_kernel(const float* __restrict__ scores, const float* __restrict__ bv,
                    __hip_bfloat16* __restrict__ p, float* __restrict__ pb)
{
  const int row = blockIdx.x;  // b*512 + k
  const int tid = threadIdx.x;
  const float s0 = scores[(size_t)row * 512 + tid];
  const float s1 = scores[(size_t)row * 512 + 256 + tid];
  __shared__ float red[4];

  float m = fmaxf(s0, s1);
#pragma unroll
  for (int off = 32; off; off >>= 1) m = fmaxf(m, __shfl_xor(m, off));
  if ((tid & 63) == 0) red[tid >> 6] = m;
  __syncthreads();
  m = fmaxf(fmaxf(red[0], red[1]), fmaxf(red[2], red[3]));

  float e0 = __expf(s0 - m), e1 = __expf(s1 - m);
  float s = e0 + e1;
#pragma unroll
  for (int off = 32; off; off >>= 1) s += __shfl_xor(s, off);
  __syncthreads();
  if ((tid & 63) == 0) red[tid >> 6] = s;
  __syncthreads();
  s = red[0] + red[1] + red[2] + red[3];
  float inv = 1.0f / s;

  float p0 = e0 * inv, p1v = e1 * inv;
  p[(size_t)row * 512 + tid] = __float2bfloat16(p0);
  p[(size_t)row * 512 + 256 + tid] = __float2bfloat16(p1v);

  float contrib = p0 * bv[tid] + p1v * bv[256 + tid];
#pragma unroll
  for (int off = 32; off; off >>= 1) contrib += __shfl_xor(contrib, off);
  __syncthreads();
  if ((tid & 63) == 0) red[tid >> 6] = contrib;
  __syncthreads();
  if (tid == 0) pb[row] = red[0] + red[1] + red[2] + red[3];
}

// ----------------------------------------------------------------------------
extern "C" void kernel_launch(void* const* d_in, const int* in_sizes, int n_in,
                              void* d_out, int out_size, void* d_ws, size_t ws_size,
                              hipStream_t stream)
{
  const float* x   = (const float*)d_in[0];
  const float* Wqk = (const float*)d_in[1];
  const float* bqk = (const float*)d_in[2];
  const float* Wv  = (const float*)d_in[3];
  const float* bv  = (const float*)d_in[4];
  float* out = (float*)d_out;

  char* w = (char*)d_ws;
  auto alloc = [&](size_t bytes) {
    void* pp = (void*)w;
    w += (bytes + 255) & ~(size_t)255;
    return pp;
  };
  __hip_bfloat16* xh     = (__hip_bfloat16*)alloc((size_t)BB * CC * TT * 2);
  __hip_bfloat16* xhT    = (__hip_bfloat16*)alloc((size_t)BB * TT * CC * 2);
  short*          Gpart  = (short*)alloc((size_t)BB * 4 * CC * CC * 2);
  short*          Gb     = (short*)alloc((size_t)BB * CC * CC * 2);
  __hip_bfloat16* S2     = (__hip_bfloat16*)alloc((size_t)BB * CC * CC * 2);
  float*          scores = (float*)alloc((size_t)BB * CC * CC * 4);
  __hip_bfloat16* pmat   = (__hip_bfloat16*)alloc((size_t)BB * CC * CC * 2);
  __hip_bfloat16* Mm     = (__hip_bfloat16*)alloc((size_t)BB * CC * CC * 2);
  __hip_bfloat16* Wqkh   = (__hip_bfloat16*)alloc((size_t)CC * CC * 2);
  __hip_bfloat16* Wvh    = (__hip_bfloat16*)alloc((size_t)CC * CC * 2);
  __hip_bfloat16* WvT    = (__hip_bfloat16*)alloc((size_t)CC * CC * 2);
  float* sx = (float*)alloc((size_t)BB * CC * 4);
  float* ta = (float*)alloc((size_t)BB * CC * 4);
  float* tb = (float*)alloc((size_t)BB * CC * 4);
  float* pb = (float*)alloc((size_t)BB * CC * 4);

  hipMemsetAsync(sx, 0, (size_t)BB * CC * 4, stream);

  // conversions + fused row-sum + small precomputes
  convert_x_kernel<<<dim3(TT / 32, CC / 32, BB), 256, 0, stream>>>(x, xh, xhT, sx);
  convert_w_kernel<<<(CC * CC) / 256, 256, 0, stream>>>(Wqk, Wv, Wqkh, Wvh, WvT);
  tatb_kernel<<<(2 * BB * CC) / 4, 256, 0, stream>>>(Wqk, Wv, sx, ta, tb);

  const long sXH = (long)CC * TT;   // 512*4096
  const long sSq = (long)CC * CC;   // 512*512

  // G = x x^T, split-K=4: grid(4,4,32), bf16 partials z-indexed
  gemm_nt_kernel<128, 128, 0><<<dim3(4, 4, BB * 4), 256, 0, stream>>>(
      xh, sXH, TT, xh, sXH, TT, Gpart, sSq, CC, 1024, 4,
      nullptr, nullptr, nullptr, nullptr);
  reduce_g_kernel<<<(BB * CC * CC) / (256 * 8), 256, 0, stream>>>(Gpart, Gb);

  // S2 = Wv G (NT: A=Wvh, B=G)
  gemm_nt_kernel<64, 64, 0><<<dim3(8, 8, BB), 256, 0, stream>>>(
      Wvh, 0, CC, (const __hip_bfloat16*)Gb, sSq, CC, S2, sSq, CC, 512, 1,
      nullptr, nullptr, nullptr, nullptr);

  // scores = (Wqk S2^T + biases)/512 (NT: A=Wqkh, B=S2)
  gemm_nt_kernel<64, 64, 1><<<dim3(8, 8, BB), 256, 0, stream>>>(
      Wqkh, 0, CC, S2, sSq, CC, scores, sSq, CC, 512, 1,
      bqk, bv, ta, tb);

  // softmax + pb
  softmax_kernel<<<BB * CC, 256, 0, stream>>>(scores, bv, pmat, pb);

  // M = p Wv (NT: A=p, B=WvT)
  gemm_nt_kernel<64, 64, 0><<<dim3(8, 8, BB), 256, 0, stream>>>(
      pmat, sSq, CC, WvT, 0, CC, Mm, sSq, CC, 512, 1,
      nullptr, nullptr, nullptr, nullptr);

  // out = M x + pb (NT: A=M, B=xhT)
  gemm_nt_kernel<128, 128, 2><<<dim3(TT / 128, 4, BB), 256, 0, stream>>>(
      Mm, sSq, CC, xhT, (long)TT * CC, CC, out, (long)CC * TT, TT, 512, 1,
      pb, nullptr, nullptr, nullptr);
}

// Round 4
// 214.165 us; speedup vs baseline: 1.4237x; 1.1088x over previous
//
#include <hip/hip_runtime.h>
#include <hip/hip_bf16.h>

// Gram-trick pipeline (B=8, C=512, T=4096, SCALE=512):
//   sx[b,c]   = sum_t x[b,c,t]           (fused into streaming convert)
//   G[b]      = x_b x_b^T                (bf16 MFMA, split-K=4 + reduce)
//   S2[b]     = Wv G[b]                  (NT 64^2)
//   scores[b] = (Wqk S2^T + bqk tb^T + ta bv^T + T bqk bv^T)/512
//   p         = softmax_v(scores); pb = p . bv
//   M[b]      = p Wv                     (NT with WvT)
//   out[b]    = M[b] x_b + pb            (NN: B=xh via subtiled LDS + ds_read_b64_tr_b16)

#define BB 8
#define CC 512
#define TT 4096

typedef __attribute__((ext_vector_type(8))) short bf16x8;
typedef __attribute__((ext_vector_type(4))) short bf16x4;
typedef __attribute__((ext_vector_type(4))) float f32x4;

__device__ __forceinline__ void gload_lds16(const void* g, void* l) {
  __builtin_amdgcn_global_load_lds((const __attribute__((address_space(1))) void*)g,
                                   (__attribute__((address_space(3))) void*)l,
                                   16, 0, 0);
}
__device__ __forceinline__ float bf2f(short u) {
  return __uint_as_float(((unsigned)(unsigned short)u) << 16);
}
__device__ __forceinline__ unsigned short f2bf(float f) {
  return __builtin_bit_cast(unsigned short, __float2bfloat16(f));
}

// ---- streaming convert x -> bf16 [c,t] + fused row-sum ---------------------
__global__ __launch_bounds__(256)
void convert_stream_kernel(const float* __restrict__ x, __hip_bfloat16* __restrict__ xh,
                           float* __restrict__ sx)
{
  const int gid = blockIdx.x * 256 + threadIdx.x;
#pragma unroll
  for (int it = 0; it < 4; it++) {
    const int chunk = it * 524288 + gid;          // 8-float chunk index
    const size_t base = (size_t)chunk * 8;
    const float4 a = *(const float4*)&x[base];
    const float4 c = *(const float4*)&x[base + 4];
    bf16x8 h;
    h[0] = (short)f2bf(a.x); h[1] = (short)f2bf(a.y);
    h[2] = (short)f2bf(a.z); h[3] = (short)f2bf(a.w);
    h[4] = (short)f2bf(c.x); h[5] = (short)f2bf(c.y);
    h[6] = (short)f2bf(c.z); h[7] = (short)f2bf(c.w);
    *(bf16x8*)&xh[base] = h;
    float s = ((a.x + a.y) + (a.z + a.w)) + ((c.x + c.y) + (c.z + c.w));
#pragma unroll
    for (int off = 32; off; off >>= 1) s += __shfl_xor(s, off);
    if ((threadIdx.x & 63) == 0) atomicAdd(&sx[chunk >> 9], s);  // 512 chunks/row, wave-uniform row
  }
}

// ---- weights -> bf16 (and Wv transposed) -----------------------------------
__global__ __launch_bounds__(256)
void convert_w_kernel(const float* __restrict__ Wqk, const float* __restrict__ Wv,
                      __hip_bfloat16* __restrict__ Wqkh, __hip_bfloat16* __restrict__ Wvh,
                      __hip_bfloat16* __restrict__ WvT)
{
  int i = blockIdx.x * 256 + threadIdx.x;  // < 512*512
  Wqkh[i] = __float2bfloat16(Wqk[i]);
  float wv = Wv[i];
  Wvh[i] = __float2bfloat16(wv);
  WvT[(i & 511) * 512 + (i >> 9)] = __float2bfloat16(wv);
}

// ---- ta[b,k] = Wqk . sx_b ; tb[b,v] = Wv . sx_b ----------------------------
__global__ __launch_bounds__(256)
void tatb_kernel(const float* __restrict__ Wqk, const float* __restrict__ Wv,
                 const float* __restrict__ sx, float* __restrict__ ta, float* __restrict__ tb)
{
  int wid = threadIdx.x >> 6, lane = threadIdx.x & 63;
  int gid = blockIdx.x * 4 + wid;          // [0, 2*BB*512)
  int which = gid >> 12;                   // BB*512 = 4096
  int rem = gid & 4095;
  int b = rem >> 9, j = rem & 511;
  const float* W = which ? Wv : Wqk;
  float s = 0.f;
#pragma unroll
  for (int i = 0; i < 8; i++) {
    int c = lane + i * 64;
    s += W[j * 512 + c] * sx[b * 512 + c];
  }
#pragma unroll
  for (int off = 32; off; off >>= 1) s += __shfl_xor(s, off);
  if (lane == 0) (which ? tb : ta)[b * 512 + j] = s;
}

// ---- NT GEMM template: C = A[M,K] B[N,K]^T, 2-phase pipelined dbuf ---------
template <int BM, int BN, int EPI>
__global__ __launch_bounds__(256)
void gemm_nt_kernel(const __hip_bfloat16* __restrict__ A, long strideA, int ldA,
                    const __hip_bfloat16* __restrict__ B, long strideB, int ldB,
                    void* __restrict__ C, long strideC, int ldC,
                    int Kslice, int nslices,
                    const float* __restrict__ p1, const float* __restrict__ p2,
                    const float* __restrict__ p3, const float* __restrict__ p4)
{
  constexpr int FM = BM / 32, FN = BN / 32;
  const int tid = threadIdx.x, lane = tid & 63, wid = tid >> 6;

  const int gx = gridDim.x, gy = gridDim.y;
  const int lin = blockIdx.x + gx * (blockIdx.y + gy * blockIdx.z);
  const int nwg = gx * gy * (int)gridDim.z;
  const int lin2 = (lin & 7) * (nwg >> 3) + (lin >> 3);
  const int tn = lin2 % gx;
  const int r1 = lin2 / gx;
  const int tm = r1 % gy;
  const int z  = r1 / gy;
  const int b  = z / nslices;
  const int ks = z - b * nslices;

  const __hip_bfloat16* Ab = A + (size_t)b * strideA + (size_t)(tm * BM) * ldA + (size_t)ks * Kslice;
  const __hip_bfloat16* Bb = B + (size_t)b * strideB + (size_t)(tn * BN) * ldB + (size_t)ks * Kslice;

  __shared__ __align__(16) __hip_bfloat16 sA[2][BM * 64];
  __shared__ __align__(16) __hip_bfloat16 sB[2][BN * 64];

  const int wr = wid >> 1, wc = wid & 1;

  f32x4 acc[FM][FN];
#pragma unroll
  for (int m = 0; m < FM; m++)
#pragma unroll
    for (int n = 0; n < FN; n++) acc[m][n] = (f32x4){0.f, 0.f, 0.f, 0.f};

  auto stage = [&](int buf, int k0) {
#pragma unroll
    for (int i = 0; i < BM / 32; i++) {
      int e = tid * 8 + i * 2048;
      int row = e >> 6, colg = (e & 63) ^ ((row & 7) << 3);
      gload_lds16(Ab + (size_t)row * ldA + k0 + colg, &sA[buf][wid * 512 + i * 2048]);
    }
#pragma unroll
    for (int i = 0; i < BN / 32; i++) {
      int e = tid * 8 + i * 2048;
      int row = e >> 6, colg = (e & 63) ^ ((row & 7) << 3);
      gload_lds16(Bb + (size_t)row * ldB + k0 + colg, &sB[buf][wid * 512 + i * 2048]);
    }
  };

  stage(0, 0);
  __syncthreads();
  const int nsteps = Kslice >> 6;
  for (int s = 0; s < nsteps; s++) {
    if (s + 1 < nsteps) stage((s + 1) & 1, (s + 1) << 6);
    const __hip_bfloat16* cA = sA[s & 1];
    const __hip_bfloat16* cB = sB[s & 1];
#pragma unroll
    for (int ks2 = 0; ks2 < 2; ks2++) {
      bf16x8 af[FM], bfv[FN];
      const int kb = ks2 * 32 + (lane >> 4) * 8;
#pragma unroll
      for (int m = 0; m < FM; m++) {
        int row = wr * (BM / 2) + m * 16 + (lane & 15);
        af[m] = *(const bf16x8*)&cA[row * 64 + (kb ^ ((row & 7) << 3))];
      }
#pragma unroll
      for (int n = 0; n < FN; n++) {
        int row = wc * (BN / 2) + n * 16 + (lane & 15);
        bfv[n] = *(const bf16x8*)&cB[row * 64 + (kb ^ ((row & 7) << 3))];
      }
#pragma unroll
      for (int m = 0; m < FM; m++)
#pragma unroll
        for (int n = 0; n < FN; n++)
          acc[m][n] = __builtin_amdgcn_mfma_f32_16x16x32_bf16(af[m], bfv[n], acc[m][n], 0, 0, 0);
    }
    __syncthreads();
  }

  // epilogue: C/D layout 16x16x32: col = lane&15, row = (lane>>4)*4 + reg
  const int rb = tm * BM + wr * (BM / 2) + ((lane >> 4) << 2);
  const int cb = tn * BN + wc * (BN / 2) + (lane & 15);

  if (EPI == 0) {
    __hip_bfloat16* Cb = (__hip_bfloat16*)C + (size_t)z * strideC;
#pragma unroll
    for (int m = 0; m < FM; m++)
#pragma unroll
      for (int n = 0; n < FN; n++)
#pragma unroll
        for (int r = 0; r < 4; r++) {
          int row = rb + m * 16 + r, col = cb + n * 16;
          Cb[(size_t)row * ldC + col] = __float2bfloat16(acc[m][n][r]);
        }
  } else if (EPI == 1) {
    float* Cf = (float*)C + (size_t)z * strideC;
    const float* ta = p3 + b * 512;
    const float* tb = p4 + b * 512;
#pragma unroll
    for (int m = 0; m < FM; m++)
#pragma unroll
      for (int n = 0; n < FN; n++)
#pragma unroll
        for (int r = 0; r < 4; r++) {
          int row = rb + m * 16 + r, col = cb + n * 16;
          float bq = p1[row], bvv = p2[col];
          float v = acc[m][n][r] + bq * tb[col] + bvv * ta[row] + (float)TT * bq * bvv;
          Cf[(size_t)row * ldC + col] = v * (1.0f / 512.0f);
        }
  } else {
    float* Cf = (float*)C + (size_t)z * strideC;
    const float* pb = p1 + b * 512;
#pragma unroll
    for (int m = 0; m < FM; m++)
#pragma unroll
      for (int n = 0; n < FN; n++)
#pragma unroll
        for (int r = 0; r < 4; r++) {
          int row = rb + m * 16 + r, col = cb + n * 16;
          Cf[(size_t)row * ldC + col] = acc[m][n][r] + pb[row];
        }
  }
}

// ---- reduce split-K bf16 partials -> bf16 G --------------------------------
__global__ __launch_bounds__(256)
void reduce_g_kernel(const short* __restrict__ Gpart, short* __restrict__ Gb)
{
  const int idx = (blockIdx.x * 256 + threadIdx.x) * 8;  // < BB*262144
  const int b = idx >> 18, i = idx & 262143;
  const short* base = Gpart + ((size_t)(b * 4) << 18) + i;
  float s[8];
#pragma unroll
  for (int q = 0; q < 8; q++) s[q] = 0.f;
#pragma unroll
  for (int ks = 0; ks < 4; ks++) {
    bf16x8 v = *(const bf16x8*)(base + ((size_t)ks << 18));
#pragma unroll
    for (int q = 0; q < 8; q++) s[q] += bf2f(v[q]);
  }
  bf16x8 o;
#pragma unroll
  for (int q = 0; q < 8; q++) o[q] = (short)f2bf(s[q]);
  *(bf16x8*)(Gb + ((size_t)b << 18) + i) = o;
}

// ---- softmax over v (512) + pb = p . bv ------------------------------------
__global__ __launch_bounds__(256)
void softmax_kernel(const float* __restrict__ scores, const float* __restrict__ bv,
                    __hip_bfloat16* __restrict__ p, float* __restrict__ pb)
{
  const int row = blockIdx.x;  // b*512 + k
  const int tid = threadIdx.x;
  const float s0 = scores[(size_t)row * 512 + tid];
  const float s1 = scores[(size_t)row * 512 + 256 + tid];
  __shared__ float red[4];

  float m = fmaxf(s0, s1);
#pragma unroll
  for (int off = 32; off; off >>= 1) m = fmaxf(m, __shfl_xor(m, off));
  if ((tid & 63) == 0) red[tid >> 6] = m;
  __syncthreads();
  m = fmaxf(fmaxf(red[0], red[1]), fmaxf(red[2], red[3]));

  float e0 = __expf(s0 - m), e1 = __expf(s1 - m);
  float s = e0 + e1;
#pragma unroll
  for (int off = 32; off; off >>= 1) s += __shfl_xor(s, off);
  __syncthreads();
  if ((tid & 63) == 0) red[tid >> 6] = s;
  __syncthreads();
  s = red[0] + red[1] + red[2] + red[3];
  float inv = 1.0f / s;

  float p0 = e0 * inv, p1v = e1 * inv;
  p[(size_t)row * 512 + tid] = __float2bfloat16(p0);
  p[(size_t)row * 512 + 256 + tid] = __float2bfloat16(p1v);

  float contrib = p0 * bv[tid] + p1v * bv[256 + tid];
#pragma unroll
  for (int off = 32; off; off >>= 1) contrib += __shfl_xor(contrib, off);
  __syncthreads();
  if ((tid & 63) == 0) red[tid >> 6] = contrib;
  __syncthreads();
  if (tid == 0) pb[row] = red[0] + red[1] + red[2] + red[3];
}

// ---- out = M x + pb : NN GEMM, B=xh[v,t] via subtiled LDS + ds_read_b64_tr_b16
// Subtiled B layout: elem (v,t) at L = ((v>>2)*8 + (t>>4))*64 + (v&3)*16 + (t&15)
// tr_read: HW transposes the 128B window covered by the 16-lane group's
// addresses; NO internal lane offset. Per-lane addr must therefore be
//   base + (lane>>4)*2048 + (lane&15)*8 + wc*512   [bytes]
// (group stride 2048B = 16 subtiles = v+=8; lane column offset explicit).
// Immediates: buf*16384 + ks2*8192 (v+=32) + n*128 (t+=16) + {0,1024} (v+=4).
__global__ __launch_bounds__(256)
void gemm_out_kernel(const __hip_bfloat16* __restrict__ Mall,
                     const __hip_bfloat16* __restrict__ xh,
                     const float* __restrict__ pball,
                     float* __restrict__ out)
{
  __shared__ __align__(16) __hip_bfloat16 sA[2][128 * 64];
  __shared__ __align__(16) __hip_bfloat16 sB[2][64 * 128];

  const int tid = threadIdx.x, lane = tid & 63, wid = tid >> 6;
  const int wr = wid >> 1, wc = wid & 1;

  // XCD swizzle over grid (32,4,8) = 1024 blocks
  const int lin = blockIdx.x + 32 * (blockIdx.y + 4 * blockIdx.z);
  const int lin2 = (lin & 7) * 128 + (lin >> 3);
  const int tn = lin2 & 31;
  const int tm = (lin2 >> 5) & 3;
  const int b  = lin2 >> 7;

  const __hip_bfloat16* Ab = Mall + (size_t)b * 262144 + (size_t)(tm * 128) * 512;
  const __hip_bfloat16* Bb = xh + (size_t)b * ((size_t)CC * TT) + tn * 128;

  f32x4 acc[4][4];
#pragma unroll
  for (int m = 0; m < 4; m++)
#pragma unroll
    for (int n = 0; n < 4; n++) acc[m][n] = (f32x4){0.f, 0.f, 0.f, 0.f};

  auto stage = [&](int buf, int k0) {
#pragma unroll
    for (int i = 0; i < 4; i++) {   // A: [128 k][64 v] swizzled
      int e = tid * 8 + i * 2048;
      int row = e >> 6, colg = (e & 63) ^ ((row & 7) << 3);
      gload_lds16(Ab + (size_t)row * 512 + k0 + colg, &sA[buf][wid * 512 + i * 2048]);
    }
#pragma unroll
    for (int q = 0; q < 4; q++) {   // B: [64 v][128 t] in subtiled layout
      int E = q * 2048 + tid * 8;
      int v = ((E >> 9) << 2) | ((E >> 4) & 3);
      int t = (((E >> 6) & 7) << 4) | (E & 8);
      gload_lds16(Bb + (size_t)(k0 + v) * TT + t, &sB[buf][wid * 512 + q * 2048]);
    }
  };

  const unsigned sB32 =
      (unsigned)(size_t)(__attribute__((address_space(3))) __hip_bfloat16*)&sB[0][0];
  const unsigned btr_lo = sB32 + (lane >> 4) * 2048 + (lane & 15) * 8 + wc * 512;  // ks2=0
  const unsigned btr_hi = btr_lo + 8192;                                           // ks2=1

#define COMPUTE(BUF)                                                            \
  {                                                                             \
    _Pragma("unroll")                                                           \
    for (int ks2 = 0; ks2 < 2; ks2++) {                                         \
      bf16x8 af[4]; bf16x4 blo[4], bhi[4];                                      \
      const int kb = ks2 * 32 + (lane >> 4) * 8;                                \
      _Pragma("unroll")                                                         \
      for (int m = 0; m < 4; m++) {                                             \
        int row = wr * 64 + m * 16 + (lane & 15);                               \
        af[m] = *(const bf16x8*)&sA[BUF][row * 64 + (kb ^ ((row & 7) << 3))];   \
      }                                                                         \
      unsigned ab = ks2 ? btr_hi : btr_lo;                                      \
      _Pragma("unroll")                                                         \
      for (int n = 0; n < 4; n++) {                                             \
        asm volatile("ds_read_b64_tr_b16 %0, %1 offset:%2"                      \
                     : "=v"(blo[n]) : "v"(ab), "i"((BUF) * 16384 + n * 128));   \
        asm volatile("ds_read_b64_tr_b16 %0, %1 offset:%2"                      \
                     : "=v"(bhi[n]) : "v"(ab), "i"((BUF) * 16384 + n * 128 + 1024)); \
      }                                                                         \
      asm volatile("s_waitcnt lgkmcnt(0)" ::: "memory");                        \
      __builtin_amdgcn_sched_barrier(0);                                        \
      _Pragma("unroll")                                                         \
      for (int m = 0; m < 4; m++)                                               \
        _Pragma("unroll")                                                       \
        for (int n = 0; n < 4; n++) {                                           \
          bf16x8 b8 = __builtin_shufflevector(blo[n], bhi[n], 0, 1, 2, 3, 4, 5, 6, 7); \
          acc[m][n] = __builtin_amdgcn_mfma_f32_16x16x32_bf16(af[m], b8, acc[m][n], 0, 0, 0); \
        }                                                                       \
    }                                                                           \
  }

  stage(0, 0);
  __syncthreads();
#pragma unroll 1
  for (int s = 0; s < 8; s += 2) {
    if (s + 1 < 8) stage(1, (s + 1) * 64);
    COMPUTE(0);
    __syncthreads();
    if (s + 2 < 8) stage(0, (s + 2) * 64);
    COMPUTE(1);
    __syncthreads();
  }
#undef COMPUTE

  // epilogue: out[b][k][t] fp32 + pb[k]
  const int rb = tm * 128 + wr * 64 + ((lane >> 4) << 2);
  const int cb = tn * 128 + wc * 64 + (lane & 15);
  float* Cf = out + (size_t)b * ((size_t)CC * TT);
  const float* pb = pball + b * 512;
#pragma unroll
  for (int m = 0; m < 4; m++)
#pragma unroll
    for (int n = 0; n < 4; n++)
#pragma unroll
      for (int r = 0; r < 4; r++) {
        int row = rb + m * 16 + r, col = cb + n * 16;
        Cf[(size_t)row * TT + col] = acc[m][n][r] + pb[row];
      }
}

// ----------------------------------------------------------------------------
extern "C" void kernel_launch(void* const* d_in, const int* in_sizes, int n_in,
                              void* d_out, int out_size, void* d_ws, size_t ws_size,
                              hipStream_t stream)
{
  const float* x   = (const float*)d_in[0];
  const float* Wqk = (const float*)d_in[1];
  const float* bqk = (const float*)d_in[2];
  const float* Wv  = (const float*)d_in[3];
  const float* bv  = (const float*)d_in[4];
  float* out = (float*)d_out;

  char* w = (char*)d_ws;
  auto alloc = [&](size_t bytes) {
    void* pp = (void*)w;
    w += (bytes + 255) & ~(size_t)255;
    return pp;
  };
  __hip_bfloat16* xh     = (__hip_bfloat16*)alloc((size_t)BB * CC * TT * 2);
  short*          Gpart  = (short*)alloc((size_t)BB * 4 * CC * CC * 2);
  short*          Gb     = (short*)alloc((size_t)BB * CC * CC * 2);
  __hip_bfloat16* S2     = (__hip_bfloat16*)alloc((size_t)BB * CC * CC * 2);
  float*          scores = (float*)alloc((size_t)BB * CC * CC * 4);
  __hip_bfloat16* pmat   = (__hip_bfloat16*)alloc((size_t)BB * CC * CC * 2);
  __hip_bfloat16* Mm     = (__hip_bfloat16*)alloc((size_t)BB * CC * CC * 2);
  __hip_bfloat16* Wqkh   = (__hip_bfloat16*)alloc((size_t)CC * CC * 2);
  __hip_bfloat16* Wvh    = (__hip_bfloat16*)alloc((size_t)CC * CC * 2);
  __hip_bfloat16* WvT    = (__hip_bfloat16*)alloc((size_t)CC * CC * 2);
  float* sx = (float*)alloc((size_t)BB * CC * 4);
  float* ta = (float*)alloc((size_t)BB * CC * 4);
  float* tb = (float*)alloc((size_t)BB * CC * 4);
  float* pb = (float*)alloc((size_t)BB * CC * 4);

  hipMemsetAsync(sx, 0, (size_t)BB * CC * 4, stream);

  convert_stream_kernel<<<2048, 256, 0, stream>>>(x, xh, sx);
  convert_w_kernel<<<(CC * CC) / 256, 256, 0, stream>>>(Wqk, Wv, Wqkh, Wvh, WvT);
  tatb_kernel<<<(2 * BB * CC) / 4, 256, 0, stream>>>(Wqk, Wv, sx, ta, tb);

  const long sXH = (long)CC * TT;
  const long sSq = (long)CC * CC;

  // G = x x^T, split-K=4
  gemm_nt_kernel<128, 128, 0><<<dim3(4, 4, BB * 4), 256, 0, stream>>>(
      xh, sXH, TT, xh, sXH, TT, Gpart, sSq, CC, 1024, 4,
      nullptr, nullptr, nullptr, nullptr);
  reduce_g_kernel<<<(BB * CC * CC) / (256 * 8), 256, 0, stream>>>(Gpart, Gb);

  // S2 = Wv G
  gemm_nt_kernel<64, 64, 0><<<dim3(8, 8, BB), 256, 0, stream>>>(
      Wvh, 0, CC, (const __hip_bfloat16*)Gb, sSq, CC, S2, sSq, CC, 512, 1,
      nullptr, nullptr, nullptr, nullptr);

  // scores = (Wqk S2^T + biases)/512
  gemm_nt_kernel<64, 64, 1><<<dim3(8, 8, BB), 256, 0, stream>>>(
      Wqkh, 0, CC, S2, sSq, CC, scores, sSq, CC, 512, 1,
      bqk, bv, ta, tb);

  softmax_kernel<<<BB * CC, 256, 0, stream>>>(scores, bv, pmat, pb);

  // M = p Wv
  gemm_nt_kernel<64, 64, 0><<<dim3(8, 8, BB), 256, 0, stream>>>(
      pmat, sSq, CC, WvT, 0, CC, Mm, sSq, CC, 512, 1,
      nullptr, nullptr, nullptr, nullptr);

  // out = M x + pb (NN, tr_b16 staging of xh)
  gemm_out_kernel<<<dim3(32, 4, 8), 256, 0, stream>>>(Mm, xh, pb, out);
}